// Round 8
// baseline (16018.225 us; speedup 1.0000x reference)
//
#include <hip/hip_runtime.h>

// B=2048, T=96, D_IN=64, H=256, L=2, K=20
// R8: WEIGHT-STATIONARY rewrite. R1-R7 evidence: step time ~90us regardless of
// per-block work, layout, or spills -> serial latency chain re-streaming 1.7MB of
// weights per step per CU. Fix: split the 1024 gate-rows across 16 blocks (64
// rows = 104KB weight slice, LDS-resident, loaded ONCE). 16 blocks/group share
// 128 batch rows; h0/h1 exchanged via global (ping-pong) + device-scope flag
// sync (2 per step). 16 groups x 16 blocks = 256 blocks x 512 thr, 1 block/CU,
// cooperative launch (co-residency guaranteed -> spin is safe).
// Wave w owns m-tile w (16 batch rows); per kk: 4 B-frags (gates) from LDS +
// 1 A-frag from global(L2) -> 4 MFMA. Thread owns all 4 gates of (row, jj) ->
// cell is register math; c stays in VGPRs.

typedef __attribute__((ext_vector_type(8))) short short8v;   // 8 x bf16
typedef __attribute__((ext_vector_type(4))) float f32x4;

#define HBUF 524288        // elems per H ping-pong buffer: 16 grp *128*256
#define GSTRIDE 32768      // elems per group in H buffer: 128*256

static __device__ __forceinline__ unsigned short f2bf(float f) {
  unsigned int u = __float_as_uint(f);
  u += 0x7fffu + ((u >> 16) & 1u);   // RNE
  return (unsigned short)(u >> 16);
}
static __device__ __forceinline__ float bf2f(unsigned short u) {
  return __uint_as_float(((unsigned int)u) << 16);
}
static __device__ __forceinline__ float sigf(float x) { return 1.f / (1.f + __expf(-x)); }
static __device__ __forceinline__ float tanhfast(float x) {
  float xc = fminf(fmaxf(x, -15.f), 15.f);
  float e = __expf(2.f * xc);
  return (e - 1.f) / (e + 1.f);
}
static __device__ __forceinline__ float softplusf(float x) {
  return (x > 0.f) ? (x + log1pf(expf(-x))) : log1pf(expf(x));
}

// ---------------- prep: fragment-major per-slice weights, biases ----------------
// W0f[s][g][kk(10)][lane(64)][8] : n = g*256+16s+(lane&15), k = kk*32+(lane>>4)*8+e
// W1f[s][g][kk(16)][lane(64)][8]
// WpF[o(21)][k(512)] bf16 (k = interleaved hp index)
__global__ void prep_kernel(const float* __restrict__ Wih0, const float* __restrict__ Whh0,
                            const float* __restrict__ Wih1, const float* __restrict__ Whh1,
                            const float* __restrict__ bih0, const float* __restrict__ bhh0,
                            const float* __restrict__ bih1, const float* __restrict__ bhh1,
                            const float* __restrict__ Wpb,  const float* __restrict__ Wpg,
                            unsigned short* __restrict__ W0, unsigned short* __restrict__ W1,
                            unsigned short* __restrict__ Wp,
                            float* __restrict__ bias0, float* __restrict__ bias1) {
  int i = blockIdx.x * 256 + threadIdx.x;
  if (i < 327680) {            // W0f: 16 slices * 20480
    int s = i / 20480, rem = i % 20480;
    int g = rem / 5120, rem2 = rem % 5120;
    int kk = rem2 >> 9, lane = (rem2 >> 3) & 63, e = rem2 & 7;
    int n = g * 256 + s * 16 + (lane & 15);
    int k = kk * 32 + (lane >> 4) * 8 + e;
    float v = (k < 64) ? Wih0[n * 64 + k] : Whh0[n * 256 + (k - 64)];
    W0[i] = f2bf(v);
    return;
  }
  i -= 327680;
  if (i < 524288) {            // W1f: 16 slices * 32768
    int s = i >> 15, rem = i & 32767;
    int g = rem >> 13, rem2 = rem & 8191;
    int kk = rem2 >> 9, lane = (rem2 >> 3) & 63, e = rem2 & 7;
    int n = g * 256 + s * 16 + (lane & 15);
    int k = kk * 32 + (lane >> 4) * 8 + e;
    float v = (k < 256) ? Wih1[n * 256 + k] : Whh1[n * 256 + (k - 256)];
    W1[i] = f2bf(v);
    return;
  }
  i -= 524288;
  if (i < 10752) {             // WpF: [21][512]
    int o = i >> 9, k = i & 511;
    float v = (o == 0) ? Wpb[k] : Wpg[(o - 1) * 512 + k];
    Wp[i] = f2bf(v);
    return;
  }
  i -= 10752;
  if (i < 1024) { bias0[i] = bih0[i] + bhh0[i]; return; }
  i -= 1024;
  if (i < 1024) { bias1[i] = bih1[i] + bhh1[i]; return; }
}

// ---------------- main persistent cooperative kernel ----------------
__global__ __launch_bounds__(512, 2) void lstm_crps_kernel(
    const float* __restrict__ X,      // [2048,96,64]
    const float* __restrict__ Y,      // [2048,96]
    const unsigned short* __restrict__ W0f,
    const unsigned short* __restrict__ W1f,
    const unsigned short* __restrict__ WpF,
    const float* __restrict__ bias0, const float* __restrict__ bias1,
    const float* __restrict__ bpb, const float* __restrict__ bpg,
    unsigned short* __restrict__ H0, unsigned short* __restrict__ H1,
    int* __restrict__ flags,
    float* __restrict__ out) {
  __shared__ __align__(16) unsigned short WL0[20480];   // [4][10][64][8]  40KB
  __shared__ __align__(16) unsigned short WL1[32768];   // [4][16][64][8]  64KB
  __shared__ __align__(16) unsigned short WpL[10752];   // [21][512]       21KB
  __shared__ float PJ[8][22];
  __shared__ float bpgs[20];
  __shared__ float CB[8][24], KN[8][24];

  const int tid = threadIdx.x;
  const int w  = tid >> 6;     // wave 0..7 = m-tile
  const int l  = tid & 63;
  const int lr = l & 15;
  const int lg = l >> 4;
  const int bid = blockIdx.x;
  const int s   = bid & 15;    // gate-row slice (j-cols [16s,16s+16))
  const int grp = bid >> 4;    // batch group (rows [grp*128, grp*128+128))

  // ---- load weight slice into LDS (once)
  {
    const int4* src0 = (const int4*)(W0f + s * 20480);
    int4* dst0 = (int4*)WL0;
    for (int i = tid; i < 2560; i += 512) dst0[i] = src0[i];
    const int4* src1 = (const int4*)(W1f + s * 32768);
    int4* dst1 = (int4*)WL1;
    for (int i = tid; i < 4096; i += 512) dst1[i] = src1[i];
    const int4* srcp = (const int4*)WpF;
    int4* dstp = (int4*)WpL;
    for (int i = tid; i < 1344; i += 512) dstp[i] = srcp[i];
    if (tid < 20) bpgs[tid] = bpg[tid];
  }

  float bz0[4], bz1[4];
#pragma unroll
  for (int g = 0; g < 4; ++g) {
    int n = g * 256 + 16 * s + lr;
    bz0[g] = bias0[n];
    bz1[g] = bias1[n];
  }
  float c0s[4] = {}, c1s[4] = {};
  float lossacc = 0.f;
  const float bpbv = bpb[0];

  const int myrow = grp * 128 + w * 16 + lr;          // A-frag row
  const float* xrowp = X + (size_t)myrow * 96 * 64 + lg * 8;

  __syncthreads();

  for (int t = 0; t < 96; ++t) {
    const int cur = t & 1, prv = cur ^ 1;
    // ---- GEMM0 A prefetch: x (f32) + h0(t-1)
    float4 xa0, xa1, xb0, xb1;
    {
      const float* xp = xrowp + (size_t)t * 64;
      xa0 = *(const float4*)xp;       xa1 = *(const float4*)(xp + 4);
      xb0 = *(const float4*)(xp + 32); xb1 = *(const float4*)(xp + 36);
    }
    short8v ah[8];
    if (t > 0) {
      const unsigned short* hp = H0 + prv * HBUF + (size_t)myrow * 256 + lg * 8;
#pragma unroll
      for (int kk = 0; kk < 8; ++kk) ah[kk] = *(const short8v*)(hp + kk * 32);
    }

    f32x4 acc[4];
#pragma unroll
    for (int g = 0; g < 4; ++g) { f32x4 z = {0.f, 0.f, 0.f, 0.f}; acc[g] = z; }

    {  // x part (kk = 0,1)
      short8v a0;
      a0[0] = (short)f2bf(xa0.x); a0[1] = (short)f2bf(xa0.y);
      a0[2] = (short)f2bf(xa0.z); a0[3] = (short)f2bf(xa0.w);
      a0[4] = (short)f2bf(xa1.x); a0[5] = (short)f2bf(xa1.y);
      a0[6] = (short)f2bf(xa1.z); a0[7] = (short)f2bf(xa1.w);
#pragma unroll
      for (int g = 0; g < 4; ++g) {
        short8v b = *(const short8v*)&WL0[((g * 10 + 0) * 64 + l) * 8];
        acc[g] = __builtin_amdgcn_mfma_f32_16x16x32_bf16(a0, b, acc[g], 0, 0, 0);
      }
      short8v a1;
      a1[0] = (short)f2bf(xb0.x); a1[1] = (short)f2bf(xb0.y);
      a1[2] = (short)f2bf(xb0.z); a1[3] = (short)f2bf(xb0.w);
      a1[4] = (short)f2bf(xb1.x); a1[5] = (short)f2bf(xb1.y);
      a1[6] = (short)f2bf(xb1.z); a1[7] = (short)f2bf(xb1.w);
#pragma unroll
      for (int g = 0; g < 4; ++g) {
        short8v b = *(const short8v*)&WL0[((g * 10 + 1) * 64 + l) * 8];
        acc[g] = __builtin_amdgcn_mfma_f32_16x16x32_bf16(a1, b, acc[g], 0, 0, 0);
      }
    }
    if (t > 0) {   // h0 part (kk = 2..9); at t=0 h0=0 -> contributes nothing
#pragma unroll
      for (int kk = 0; kk < 8; ++kk)
#pragma unroll
        for (int g = 0; g < 4; ++g) {
          short8v b = *(const short8v*)&WL0[((g * 10 + 2 + kk) * 64 + l) * 8];
          acc[g] = __builtin_amdgcn_mfma_f32_16x16x32_bf16(ah[kk], b, acc[g], 0, 0, 0);
        }
    }

    // ---- LSTM cell 0 -> publish h0 slice
    {
      unsigned short* h0c = H0 + cur * HBUF + grp * GSTRIDE;
#pragma unroll
      for (int r = 0; r < 4; ++r) {
        int rowl = w * 16 + lg * 4 + r;
        float cn = sigf(acc[1][r] + bz0[1]) * c0s[r]
                 + sigf(acc[0][r] + bz0[0]) * tanhfast(acc[2][r] + bz0[2]);
        c0s[r] = cn;
        float hn = sigf(acc[3][r] + bz0[3]) * tanhfast(cn);
        h0c[rowl * 256 + 16 * s + lr] = f2bf(hn);
      }
    }
    __threadfence();
    __syncthreads();
    {
      int* f0 = flags + (t * 2 + 0) * 16 + grp;
      if (tid == 0) {
        __hip_atomic_fetch_add(f0, 1, __ATOMIC_RELEASE, __HIP_MEMORY_SCOPE_AGENT);
        while (__hip_atomic_load(f0, __ATOMIC_ACQUIRE, __HIP_MEMORY_SCOPE_AGENT) < 16)
          __builtin_amdgcn_s_sleep(1);
      }
      __syncthreads();
    }

    // ---- GEMM1 A prefetch: h0n (fresh) + h1(t-1)
    short8v a1h[16];
    {
      const unsigned short* hp0 = H0 + cur * HBUF + (size_t)myrow * 256 + lg * 8;
#pragma unroll
      for (int kk = 0; kk < 8; ++kk) a1h[kk] = *(const short8v*)(hp0 + kk * 32);
      if (t > 0) {
        const unsigned short* hp1 = H1 + prv * HBUF + (size_t)myrow * 256 + lg * 8;
#pragma unroll
        for (int kk = 0; kk < 8; ++kk) a1h[8 + kk] = *(const short8v*)(hp1 + kk * 32);
      }
    }
#pragma unroll
    for (int g = 0; g < 4; ++g) { f32x4 z = {0.f, 0.f, 0.f, 0.f}; acc[g] = z; }
#pragma unroll
    for (int kk = 0; kk < 8; ++kk)
#pragma unroll
      for (int g = 0; g < 4; ++g) {
        short8v b = *(const short8v*)&WL1[((g * 16 + kk) * 64 + l) * 8];
        acc[g] = __builtin_amdgcn_mfma_f32_16x16x32_bf16(a1h[kk], b, acc[g], 0, 0, 0);
      }
    if (t > 0) {
#pragma unroll
      for (int kk = 8; kk < 16; ++kk)
#pragma unroll
        for (int g = 0; g < 4; ++g) {
          short8v b = *(const short8v*)&WL1[((g * 16 + kk) * 64 + l) * 8];
          acc[g] = __builtin_amdgcn_mfma_f32_16x16x32_bf16(a1h[kk], b, acc[g], 0, 0, 0);
        }
    }

    // ---- LSTM cell 1 -> publish h1 slice
    {
      unsigned short* h1c = H1 + cur * HBUF + grp * GSTRIDE;
#pragma unroll
      for (int r = 0; r < 4; ++r) {
        int rowl = w * 16 + lg * 4 + r;
        float cn = sigf(acc[1][r] + bz1[1]) * c1s[r]
                 + sigf(acc[0][r] + bz1[0]) * tanhfast(acc[2][r] + bz1[2]);
        c1s[r] = cn;
        float hn = sigf(acc[3][r] + bz1[3]) * tanhfast(cn);
        h1c[rowl * 256 + 16 * s + lr] = f2bf(hn);
      }
    }
    __threadfence();
    __syncthreads();
    {
      int* f1 = flags + (t * 2 + 1) * 16 + grp;
      if (tid == 0) {
        __hip_atomic_fetch_add(f1, 1, __ATOMIC_RELEASE, __HIP_MEMORY_SCOPE_AGENT);
        while (__hip_atomic_load(f1, __ATOMIC_ACQUIRE, __HIP_MEMORY_SCOPE_AGENT) < 16)
          __builtin_amdgcn_s_sleep(1);
      }
      __syncthreads();
    }

    // ---- projection for this block's 8 rows: PJ[r][o] = hp . Wp[o] + bias
    if (tid < 168) {
      int r = tid / 21, o = tid - r * 21;
      const unsigned short* h0p = H0 + cur * HBUF + (size_t)(grp * 128 + 8 * s + r) * 256;
      const unsigned short* h1p = H1 + cur * HBUF + (size_t)(grp * 128 + 8 * s + r) * 256;
      float a = 0.f;
#pragma unroll 4
      for (int cb = 0; cb < 32; ++cb) {
        short8v v0 = *(const short8v*)(h0p + cb * 8);
        short8v v1 = *(const short8v*)(h1p + cb * 8);
        short8v w0 = *(const short8v*)&WpL[o * 512 + cb * 16];
        short8v w1 = *(const short8v*)&WpL[o * 512 + cb * 16 + 8];
#pragma unroll
        for (int e = 0; e < 4; ++e) {
          a += bf2f((unsigned short)v0[e]) * bf2f((unsigned short)w0[2 * e])
             + bf2f((unsigned short)v1[e]) * bf2f((unsigned short)w0[2 * e + 1]);
        }
#pragma unroll
        for (int e = 4; e < 8; ++e) {
          a += bf2f((unsigned short)v0[e]) * bf2f((unsigned short)w1[2 * e - 8])
             + bf2f((unsigned short)v1[e]) * bf2f((unsigned short)w1[2 * e - 7]);
        }
      }
      PJ[r][o] = a + ((o == 0) ? bpbv : bpgs[o - 1]);
    }
    __syncthreads();

    // ---- CRPS spline loss: 8 rows, one lane each (wave 0)
    if (tid < 8) {
      const int row = tid;
      const float y = Y[(size_t)(grp * 128 + 8 * s + row) * 96 + t];
      const float h = 0.05f;
      float beta0 = softplusf(PJ[row][0]);
      {  // pass 1: spline coeffs bb -> CB
        float gprev = beta0, brawprev = 0.f, ssum = 0.f, g19 = 0.f;
#pragma unroll
        for (int i2 = 0; i2 < 20; ++i2) {
          float gi = softplusf(PJ[row][1 + i2]);
          float braw = (gi - gprev) * 10.f;
          float bbv = (i2 == 0) ? braw : (braw - brawprev);
          if (i2 < 19) { ssum += bbv; CB[row][i2] = bbv; }
          gprev = gi; brawprev = braw; g19 = gi;
        }
        CB[row][19] = g19 - ssum;
      }
      {  // pass 2: knots via prefix sums
        float S0 = 0.f, S1 = 0.f, S2 = 0.f;
        KN[row][0] = 0.f;
#pragma unroll
        for (int i2 = 0; i2 < 19; ++i2) {
          float bbv = CB[row][i2];
          float fi = (float)i2;
          S0 += bbv; S1 += fi * bbv; S2 += fi * fi * bbv;
          float ip = (float)(i2 + 1);
          KN[row][i2 + 1] = ip * h * beta0 + h * h * (ip * ip * S0 - 2.f * ip * S1 + S2);
        }
      }
      float Aq = 0.f, Bk = 0.f, Ck = 0.f, crps3 = 0.f;
      float best = 1e30f; int amin = 0;
#pragma unroll
      for (int i2 = 0; i2 < 20; ++i2) {
        float knot = KN[row][i2];
        float bbv = CB[row][i2];
        float d = y - knot;
        float ad = fabsf(d);
        if (ad < best) { best = ad; amin = i2; }
        float alf = (d > 0.f) ? 1.f : 0.f;
        float ks = (float)i2 * h;
        float ab = alf * bbv;
        Aq += ab; Bk += ab * ks; Ck += ab * ks * ks;
        float om = 1.f - ks; float om2 = om * om;
        crps3 += bbv * (1.f / 6.f) * om2 * om2;
      }
      float Bc = beta0 - 2.f * Bk;
      float Cc = Ck - y;
      float disc = Bc * Bc - 4.f * Aq * Cc;
      bool az = (Aq == 0.f);
      bool qs = (!az) && (disc >= 0.f);
      float alpha;
      if (qs)      alpha = (-Bc + sqrtf(disc)) / (2.f * Aq);
      else if (az) alpha = -Cc / ((Bc == 0.f) ? 1.f : Bc);
      else         alpha = (float)amin * h;
      float crps4 = 0.f;
#pragma unroll
      for (int i2 = 0; i2 < 20; ++i2) {
        float knot = KN[row][i2];
        float bbv = CB[row][i2];
        float alf = ((y - knot) > 0.f) ? 1.f : 0.f;
        float am = alpha - (float)i2 * h;
        crps4 += alf * (2.f / 3.f) * bbv * am * am * am;
      }
      lossacc += (-y * (1.f - 2.f * alpha) + beta0 * (1.f / 3.f - alpha * alpha) + crps3 - crps4);
    }
    __syncthreads();   // PJ/CB/KN reused next step
  }

  // block reduction: lanes 0..7 of wave 0 hold loss
  if (w == 0) {
#pragma unroll
    for (int off = 4; off > 0; off >>= 1) lossacc += __shfl_down(lossacc, off, 64);
    if (l == 0) atomicAdd(out, lossacc * (1.f / 2048.f));
  }
}

extern "C" void kernel_launch(void* const* d_in, const int* in_sizes, int n_in,
                              void* d_out, int out_size, void* d_ws, size_t ws_size,
                              hipStream_t stream) {
  const float* X    = (const float*)d_in[0];
  const float* Y    = (const float*)d_in[1];
  const float* Wih0 = (const float*)d_in[2];
  const float* Whh0 = (const float*)d_in[3];
  const float* Wih1 = (const float*)d_in[4];
  const float* Whh1 = (const float*)d_in[5];
  const float* bih0 = (const float*)d_in[6];
  const float* bhh0 = (const float*)d_in[7];
  const float* bih1 = (const float*)d_in[8];
  const float* bhh1 = (const float*)d_in[9];
  const float* Wpb  = (const float*)d_in[10];
  const float* bpb  = (const float*)d_in[11];
  const float* Wpg  = (const float*)d_in[12];
  const float* bpg  = (const float*)d_in[13];

  char* ws = (char*)d_ws;
  unsigned short* W0f = (unsigned short*)(ws);                // 327680*2 = 655,360
  unsigned short* W1f = (unsigned short*)(ws + 655360);       // 524288*2 = 1,048,576
  unsigned short* WpF = (unsigned short*)(ws + 1703936);      // 10752*2  = 21,504 (pad)
  float* bias0 = (float*)(ws + 1728512);                      // 4096
  float* bias1 = (float*)(ws + 1732608);                      // 4096
  unsigned short* H0 = (unsigned short*)(ws + 1736704);       // 2*HBUF*2 = 2,097,152
  unsigned short* H1 = (unsigned short*)(ws + 3833856);       // 2,097,152
  int* flags = (int*)(ws + 5931008);                          // 96*2*16*4 = 12,288

  hipMemsetAsync(d_out, 0, sizeof(float), stream);
  hipMemsetAsync(flags, 0, 12288, stream);
  prep_kernel<<<3378, 256, 0, stream>>>(Wih0, Whh0, Wih1, Whh1, bih0, bhh0, bih1, bhh1,
                                        Wpb, Wpg, W0f, W1f, WpF, bias0, bias1);

  float* outp = (float*)d_out;
  void* kargs[] = {(void*)&X, (void*)&Y, (void*)&W0f, (void*)&W1f, (void*)&WpF,
                   (void*)&bias0, (void*)&bias1, (void*)&bpb, (void*)&bpg,
                   (void*)&H0, (void*)&H1, (void*)&flags, (void*)&outp};
  hipLaunchCooperativeKernel((const void*)lstm_crps_kernel, dim3(256), dim3(512),
                             kargs, 0, stream);
}

// Round 9
// 15087.355 us; speedup vs baseline: 1.0617x; 1.0617x over previous
//
#include <hip/hip_runtime.h>

// B=2048, T=96, D_IN=64, H=256, L=2, K=20
// R9: weight-stationary (R8) + fixes for the two R8 serializers:
//  (1) flag padding: one 128B line per (t,phase,grp). R8 had all 16 groups' flags
//      in ONE cacheline -> 256 RMW + 256 spinners on one line x192 syncs = ~8ms.
//  (2) projection bank conflicts: WpL stride 520 (banks o*4 mod 32) + o-major
//      thread map (8 lanes/o broadcast one LDS address). R8: 1.8e8 conflicts.
//  (3) h1(t-1) loads hoisted above sync A; y load above sync B.
// Structure: 16 slices x 16 groups = 256 blocks x 512 thr, coop launch, 1 blk/CU.
// Block owns 64 gate-rows (W slice LDS-resident, loaded once) and publishes its
// 16-col h0/h1 slice for the group's 128 batch rows via global ping-pong + flags.

typedef __attribute__((ext_vector_type(8))) short short8v;   // 8 x bf16
typedef __attribute__((ext_vector_type(4))) float f32x4;

#define HBUF 524288        // elems per H ping-pong buffer: 16 grp *128*256
#define GSTRIDE 32768      // elems per group in H buffer: 128*256

static __device__ __forceinline__ unsigned short f2bf(float f) {
  unsigned int u = __float_as_uint(f);
  u += 0x7fffu + ((u >> 16) & 1u);   // RNE
  return (unsigned short)(u >> 16);
}
static __device__ __forceinline__ float bf2f(unsigned short u) {
  return __uint_as_float(((unsigned int)u) << 16);
}
static __device__ __forceinline__ float sigf(float x) { return 1.f / (1.f + __expf(-x)); }
static __device__ __forceinline__ float tanhfast(float x) {
  float xc = fminf(fmaxf(x, -15.f), 15.f);
  float e = __expf(2.f * xc);
  return (e - 1.f) / (e + 1.f);
}
static __device__ __forceinline__ float softplusf(float x) {
  return (x > 0.f) ? (x + log1pf(expf(-x))) : log1pf(expf(x));
}

// ---------------- prep: fragment-major per-slice weights, biases ----------------
__global__ void prep_kernel(const float* __restrict__ Wih0, const float* __restrict__ Whh0,
                            const float* __restrict__ Wih1, const float* __restrict__ Whh1,
                            const float* __restrict__ bih0, const float* __restrict__ bhh0,
                            const float* __restrict__ bih1, const float* __restrict__ bhh1,
                            const float* __restrict__ Wpb,  const float* __restrict__ Wpg,
                            unsigned short* __restrict__ W0, unsigned short* __restrict__ W1,
                            unsigned short* __restrict__ Wp,
                            float* __restrict__ bias0, float* __restrict__ bias1) {
  int i = blockIdx.x * 256 + threadIdx.x;
  if (i < 327680) {            // W0f: [s][g][kk(10)][lane(64)][8]
    int s = i / 20480, rem = i % 20480;
    int g = rem / 5120, rem2 = rem % 5120;
    int kk = rem2 >> 9, lane = (rem2 >> 3) & 63, e = rem2 & 7;
    int n = g * 256 + s * 16 + (lane & 15);
    int k = kk * 32 + (lane >> 4) * 8 + e;
    float v = (k < 64) ? Wih0[n * 64 + k] : Whh0[n * 256 + (k - 64)];
    W0[i] = f2bf(v);
    return;
  }
  i -= 327680;
  if (i < 524288) {            // W1f: [s][g][kk(16)][lane(64)][8]
    int s = i >> 15, rem = i & 32767;
    int g = rem >> 13, rem2 = rem & 8191;
    int kk = rem2 >> 9, lane = (rem2 >> 3) & 63, e = rem2 & 7;
    int n = g * 256 + s * 16 + (lane & 15);
    int k = kk * 32 + (lane >> 4) * 8 + e;
    float v = (k < 256) ? Wih1[n * 256 + k] : Whh1[n * 256 + (k - 256)];
    W1[i] = f2bf(v);
    return;
  }
  i -= 524288;
  if (i < 10752) {             // WpF: [21][512]
    int o = i >> 9, k = i & 511;
    float v = (o == 0) ? Wpb[k] : Wpg[(o - 1) * 512 + k];
    Wp[i] = f2bf(v);
    return;
  }
  i -= 10752;
  if (i < 1024) { bias0[i] = bih0[i] + bhh0[i]; return; }
  i -= 1024;
  if (i < 1024) { bias1[i] = bih1[i] + bhh1[i]; return; }
}

// ---------------- main persistent cooperative kernel ----------------
__global__ __launch_bounds__(512, 2) void lstm_crps_kernel(
    const float* __restrict__ X,      // [2048,96,64]
    const float* __restrict__ Y,      // [2048,96]
    const unsigned short* __restrict__ W0f,
    const unsigned short* __restrict__ W1f,
    const unsigned short* __restrict__ WpF,
    const float* __restrict__ bias0, const float* __restrict__ bias1,
    const float* __restrict__ bpb, const float* __restrict__ bpg,
    unsigned short* __restrict__ H0, unsigned short* __restrict__ H1,
    int* __restrict__ flags,
    float* __restrict__ out) {
  __shared__ __align__(16) unsigned short WL0[20480];   // [4][10][64][8]  40KB
  __shared__ __align__(16) unsigned short WL1[32768];   // [4][16][64][8]  64KB
  __shared__ __align__(16) unsigned short WpL[21 * 520];// padded: bank = o*4 mod 32
  __shared__ float PJ[8][22];
  __shared__ float bpgs[20];
  __shared__ float CB[8][24], KN[8][24];

  const int tid = threadIdx.x;
  const int w  = tid >> 6;     // wave 0..7 = m-tile
  const int l  = tid & 63;
  const int lr = l & 15;
  const int lg = l >> 4;
  const int bid = blockIdx.x;
  const int s   = bid & 15;    // gate-row slice (j-cols [16s,16s+16))
  const int grp = bid >> 4;    // batch group (rows [grp*128, grp*128+128))

  // ---- load weight slice into LDS (once)
  {
    const int4* src0 = (const int4*)(W0f + s * 20480);
    int4* dst0 = (int4*)WL0;
    for (int i = tid; i < 2560; i += 512) dst0[i] = src0[i];
    const int4* src1 = (const int4*)(W1f + s * 32768);
    int4* dst1 = (int4*)WL1;
    for (int i = tid; i < 4096; i += 512) dst1[i] = src1[i];
    for (int i = tid; i < 10752; i += 512) {
      int o = i >> 9, k = i & 511;
      WpL[o * 520 + k] = WpF[i];
    }
    if (tid < 20) bpgs[tid] = bpg[tid];
  }

  float bz0[4], bz1[4];
#pragma unroll
  for (int g = 0; g < 4; ++g) {
    int n = g * 256 + 16 * s + lr;
    bz0[g] = bias0[n];
    bz1[g] = bias1[n];
  }
  float c0s[4] = {}, c1s[4] = {};
  float lossacc = 0.f;
  const float bpbv = bpb[0];

  const int myrow = grp * 128 + w * 16 + lr;          // A-frag row
  const float* xrowp = X + (size_t)myrow * 96 * 64 + lg * 8;

  __syncthreads();

  for (int t = 0; t < 96; ++t) {
    const int cur = t & 1, prv = cur ^ 1;
    // ---- GEMM0 A prefetch: x (f32) + h0(t-1)
    float4 xa0, xa1, xb0, xb1;
    {
      const float* xp = xrowp + (size_t)t * 64;
      xa0 = *(const float4*)xp;       xa1 = *(const float4*)(xp + 4);
      xb0 = *(const float4*)(xp + 32); xb1 = *(const float4*)(xp + 36);
    }
    short8v ah[8];
    if (t > 0) {
      const unsigned short* hp = H0 + prv * HBUF + (size_t)myrow * 256 + lg * 8;
#pragma unroll
      for (int kk = 0; kk < 8; ++kk) ah[kk] = *(const short8v*)(hp + kk * 32);
    }

    f32x4 acc[4];
#pragma unroll
    for (int g = 0; g < 4; ++g) { f32x4 z = {0.f, 0.f, 0.f, 0.f}; acc[g] = z; }

    {  // x part (kk = 0,1)
      short8v a0;
      a0[0] = (short)f2bf(xa0.x); a0[1] = (short)f2bf(xa0.y);
      a0[2] = (short)f2bf(xa0.z); a0[3] = (short)f2bf(xa0.w);
      a0[4] = (short)f2bf(xa1.x); a0[5] = (short)f2bf(xa1.y);
      a0[6] = (short)f2bf(xa1.z); a0[7] = (short)f2bf(xa1.w);
#pragma unroll
      for (int g = 0; g < 4; ++g) {
        short8v b = *(const short8v*)&WL0[((g * 10 + 0) * 64 + l) * 8];
        acc[g] = __builtin_amdgcn_mfma_f32_16x16x32_bf16(a0, b, acc[g], 0, 0, 0);
      }
      short8v a1;
      a1[0] = (short)f2bf(xb0.x); a1[1] = (short)f2bf(xb0.y);
      a1[2] = (short)f2bf(xb0.z); a1[3] = (short)f2bf(xb0.w);
      a1[4] = (short)f2bf(xb1.x); a1[5] = (short)f2bf(xb1.y);
      a1[6] = (short)f2bf(xb1.z); a1[7] = (short)f2bf(xb1.w);
#pragma unroll
      for (int g = 0; g < 4; ++g) {
        short8v b = *(const short8v*)&WL0[((g * 10 + 1) * 64 + l) * 8];
        acc[g] = __builtin_amdgcn_mfma_f32_16x16x32_bf16(a1, b, acc[g], 0, 0, 0);
      }
    }
    if (t > 0) {   // h0 part (kk = 2..9); at t=0 h0=0
#pragma unroll
      for (int kk = 0; kk < 8; ++kk)
#pragma unroll
        for (int g = 0; g < 4; ++g) {
          short8v b = *(const short8v*)&WL0[((g * 10 + 2 + kk) * 64 + l) * 8];
          acc[g] = __builtin_amdgcn_mfma_f32_16x16x32_bf16(ah[kk], b, acc[g], 0, 0, 0);
        }
    }

    // ---- LSTM cell 0 -> publish h0 slice
    {
      unsigned short* h0c = H0 + cur * HBUF + grp * GSTRIDE;
#pragma unroll
      for (int r = 0; r < 4; ++r) {
        int rowl = w * 16 + lg * 4 + r;
        float cn = sigf(acc[1][r] + bz0[1]) * c0s[r]
                 + sigf(acc[0][r] + bz0[0]) * tanhfast(acc[2][r] + bz0[2]);
        c0s[r] = cn;
        float hn = sigf(acc[3][r] + bz0[3]) * tanhfast(cn);
        h0c[rowl * 256 + 16 * s + lr] = f2bf(hn);
      }
    }

    // ---- hoist: h1(t-1) A-frags (independent of sync A)
    short8v a1h[16];
    if (t > 0) {
      const unsigned short* hp1 = H1 + prv * HBUF + (size_t)myrow * 256 + lg * 8;
#pragma unroll
      for (int kk = 0; kk < 8; ++kk) a1h[8 + kk] = *(const short8v*)(hp1 + kk * 32);
    }

    __threadfence();
    __syncthreads();
    {
      int* f0 = flags + ((t * 2 + 0) * 16 + grp) * 32;   // private 128B line
      if (tid == 0) {
        __hip_atomic_fetch_add(f0, 1, __ATOMIC_RELEASE, __HIP_MEMORY_SCOPE_AGENT);
        while (__hip_atomic_load(f0, __ATOMIC_ACQUIRE, __HIP_MEMORY_SCOPE_AGENT) < 16)
          __builtin_amdgcn_s_sleep(1);
      }
      __syncthreads();
    }

    // ---- GEMM1: h0n (fresh) + h1(t-1)
    {
      const unsigned short* hp0 = H0 + cur * HBUF + (size_t)myrow * 256 + lg * 8;
#pragma unroll
      for (int kk = 0; kk < 8; ++kk) a1h[kk] = *(const short8v*)(hp0 + kk * 32);
    }
#pragma unroll
    for (int g = 0; g < 4; ++g) { f32x4 z = {0.f, 0.f, 0.f, 0.f}; acc[g] = z; }
#pragma unroll
    for (int kk = 0; kk < 8; ++kk)
#pragma unroll
      for (int g = 0; g < 4; ++g) {
        short8v b = *(const short8v*)&WL1[((g * 16 + kk) * 64 + l) * 8];
        acc[g] = __builtin_amdgcn_mfma_f32_16x16x32_bf16(a1h[kk], b, acc[g], 0, 0, 0);
      }
    if (t > 0) {
#pragma unroll
      for (int kk = 8; kk < 16; ++kk)
#pragma unroll
        for (int g = 0; g < 4; ++g) {
          short8v b = *(const short8v*)&WL1[((g * 16 + kk) * 64 + l) * 8];
          acc[g] = __builtin_amdgcn_mfma_f32_16x16x32_bf16(a1h[kk], b, acc[g], 0, 0, 0);
        }
    }

    // ---- LSTM cell 1 -> publish h1 slice
    {
      unsigned short* h1c = H1 + cur * HBUF + grp * GSTRIDE;
#pragma unroll
      for (int r = 0; r < 4; ++r) {
        int rowl = w * 16 + lg * 4 + r;
        float cn = sigf(acc[1][r] + bz1[1]) * c1s[r]
                 + sigf(acc[0][r] + bz1[0]) * tanhfast(acc[2][r] + bz1[2]);
        c1s[r] = cn;
        float hn = sigf(acc[3][r] + bz1[3]) * tanhfast(cn);
        h1c[rowl * 256 + 16 * s + lr] = f2bf(hn);
      }
    }

    // ---- hoist: CRPS label load (independent of sync B)
    float yv = (tid < 8) ? Y[(size_t)(grp * 128 + 8 * s + tid) * 96 + t] : 0.f;

    __threadfence();
    __syncthreads();
    {
      int* f1 = flags + ((t * 2 + 1) * 16 + grp) * 32;
      if (tid == 0) {
        __hip_atomic_fetch_add(f1, 1, __ATOMIC_RELEASE, __HIP_MEMORY_SCOPE_AGENT);
        while (__hip_atomic_load(f1, __ATOMIC_ACQUIRE, __HIP_MEMORY_SCOPE_AGENT) < 16)
          __builtin_amdgcn_s_sleep(1);
      }
      __syncthreads();
    }

    // ---- projection: PJ[r][o] = hp . Wp[o] + bias  (o-major: 8 lanes share o)
    if (tid < 168) {
      int o = tid >> 3, r = tid & 7;
      const unsigned short* h0p = H0 + cur * HBUF + (size_t)(grp * 128 + 8 * s + r) * 256;
      const unsigned short* h1p = H1 + cur * HBUF + (size_t)(grp * 128 + 8 * s + r) * 256;
      const unsigned short* wpo = &WpL[o * 520];
      float a = 0.f;
#pragma unroll 4
      for (int cb = 0; cb < 32; ++cb) {
        short8v v0 = *(const short8v*)(h0p + cb * 8);
        short8v v1 = *(const short8v*)(h1p + cb * 8);
        short8v w0 = *(const short8v*)(wpo + cb * 16);
        short8v w1 = *(const short8v*)(wpo + cb * 16 + 8);
#pragma unroll
        for (int e = 0; e < 4; ++e) {
          a += bf2f((unsigned short)v0[e]) * bf2f((unsigned short)w0[2 * e])
             + bf2f((unsigned short)v1[e]) * bf2f((unsigned short)w0[2 * e + 1]);
        }
#pragma unroll
        for (int e = 4; e < 8; ++e) {
          a += bf2f((unsigned short)v0[e]) * bf2f((unsigned short)w1[2 * e - 8])
             + bf2f((unsigned short)v1[e]) * bf2f((unsigned short)w1[2 * e - 7]);
        }
      }
      PJ[r][o] = a + ((o == 0) ? bpbv : bpgs[o - 1]);
    }
    __syncthreads();

    // ---- CRPS spline loss: 8 rows, one lane each (wave 0)
    if (tid < 8) {
      const int row = tid;
      const float y = yv;
      const float h = 0.05f;
      float beta0 = softplusf(PJ[row][0]);
      {  // pass 1: spline coeffs bb -> CB
        float gprev = beta0, brawprev = 0.f, ssum = 0.f, g19 = 0.f;
#pragma unroll
        for (int i2 = 0; i2 < 20; ++i2) {
          float gi = softplusf(PJ[row][1 + i2]);
          float braw = (gi - gprev) * 10.f;
          float bbv = (i2 == 0) ? braw : (braw - brawprev);
          if (i2 < 19) { ssum += bbv; CB[row][i2] = bbv; }
          gprev = gi; brawprev = braw; g19 = gi;
        }
        CB[row][19] = g19 - ssum;
      }
      {  // pass 2: knots via prefix sums
        float S0 = 0.f, S1 = 0.f, S2 = 0.f;
        KN[row][0] = 0.f;
#pragma unroll
        for (int i2 = 0; i2 < 19; ++i2) {
          float bbv = CB[row][i2];
          float fi = (float)i2;
          S0 += bbv; S1 += fi * bbv; S2 += fi * fi * bbv;
          float ip = (float)(i2 + 1);
          KN[row][i2 + 1] = ip * h * beta0 + h * h * (ip * ip * S0 - 2.f * ip * S1 + S2);
        }
      }
      float Aq = 0.f, Bk = 0.f, Ck = 0.f, crps3 = 0.f;
      float best = 1e30f; int amin = 0;
#pragma unroll
      for (int i2 = 0; i2 < 20; ++i2) {
        float knot = KN[row][i2];
        float bbv = CB[row][i2];
        float d = y - knot;
        float ad = fabsf(d);
        if (ad < best) { best = ad; amin = i2; }
        float alf = (d > 0.f) ? 1.f : 0.f;
        float ks = (float)i2 * h;
        float ab = alf * bbv;
        Aq += ab; Bk += ab * ks; Ck += ab * ks * ks;
        float om = 1.f - ks; float om2 = om * om;
        crps3 += bbv * (1.f / 6.f) * om2 * om2;
      }
      float Bc = beta0 - 2.f * Bk;
      float Cc = Ck - y;
      float disc = Bc * Bc - 4.f * Aq * Cc;
      bool az = (Aq == 0.f);
      bool qs = (!az) && (disc >= 0.f);
      float alpha;
      if (qs)      alpha = (-Bc + sqrtf(disc)) / (2.f * Aq);
      else if (az) alpha = -Cc / ((Bc == 0.f) ? 1.f : Bc);
      else         alpha = (float)amin * h;
      float crps4 = 0.f;
#pragma unroll
      for (int i2 = 0; i2 < 20; ++i2) {
        float knot = KN[row][i2];
        float bbv = CB[row][i2];
        float alf = ((y - knot) > 0.f) ? 1.f : 0.f;
        float am = alpha - (float)i2 * h;
        crps4 += alf * (2.f / 3.f) * bbv * am * am * am;
      }
      lossacc += (-y * (1.f - 2.f * alpha) + beta0 * (1.f / 3.f - alpha * alpha) + crps3 - crps4);
    }
    __syncthreads();   // PJ/CB/KN reused next step
  }

  // block reduction: lanes 0..7 of wave 0 hold loss
  if (w == 0) {
#pragma unroll
    for (int off = 4; off > 0; off >>= 1) lossacc += __shfl_down(lossacc, off, 64);
    if (l == 0) atomicAdd(out, lossacc * (1.f / 2048.f));
  }
}

extern "C" void kernel_launch(void* const* d_in, const int* in_sizes, int n_in,
                              void* d_out, int out_size, void* d_ws, size_t ws_size,
                              hipStream_t stream) {
  const float* X    = (const float*)d_in[0];
  const float* Y    = (const float*)d_in[1];
  const float* Wih0 = (const float*)d_in[2];
  const float* Whh0 = (const float*)d_in[3];
  const float* Wih1 = (const float*)d_in[4];
  const float* Whh1 = (const float*)d_in[5];
  const float* bih0 = (const float*)d_in[6];
  const float* bhh0 = (const float*)d_in[7];
  const float* bih1 = (const float*)d_in[8];
  const float* bhh1 = (const float*)d_in[9];
  const float* Wpb  = (const float*)d_in[10];
  const float* bpb  = (const float*)d_in[11];
  const float* Wpg  = (const float*)d_in[12];
  const float* bpg  = (const float*)d_in[13];

  char* ws = (char*)d_ws;
  unsigned short* W0f = (unsigned short*)(ws);                // 655,360
  unsigned short* W1f = (unsigned short*)(ws + 655360);       // 1,048,576
  unsigned short* WpF = (unsigned short*)(ws + 1703936);      // 21,504 (+pad)
  float* bias0 = (float*)(ws + 1728512);                      // 4,096
  float* bias1 = (float*)(ws + 1732608);                      // 4,096
  unsigned short* H0 = (unsigned short*)(ws + 1736704);       // 2,097,152
  unsigned short* H1 = (unsigned short*)(ws + 3833856);       // 2,097,152
  int* flags = (int*)(ws + 5931008);                          // 96*2*16*32*4 = 393,216

  hipMemsetAsync(d_out, 0, sizeof(float), stream);
  hipMemsetAsync(flags, 0, 393216, stream);
  prep_kernel<<<3378, 256, 0, stream>>>(Wih0, Whh0, Wih1, Whh1, bih0, bhh0, bih1, bhh1,
                                        Wpb, Wpg, W0f, W1f, WpF, bias0, bias1);

  float* outp = (float*)d_out;
  void* kargs[] = {(void*)&X, (void*)&Y, (void*)&W0f, (void*)&W1f, (void*)&WpF,
                   (void*)&bias0, (void*)&bias1, (void*)&bpb, (void*)&bpg,
                   (void*)&H0, (void*)&H1, (void*)&flags, (void*)&outp};
  hipLaunchCooperativeKernel((const void*)lstm_crps_kernel, dim3(256), dim3(512),
                             kargs, 0, stream);
}

// Round 10
// 2779.062 us; speedup vs baseline: 5.7639x; 5.4289x over previous
//
#include <hip/hip_runtime.h>

// B=2048, T=96, D_IN=64, H=256, L=2, K=20
// R10: weight-stationary + SINGLE sync per step.
//  Schedule per iter it (0..96): {GEMM1(it-1) || GEMM0(it)} -> sync -> proj/CRPS(it-1).
//  h0 ring-4, h1 ring-2 (blocks within a group are <=1 sync apart -> no WAR).
//  Sync: syncthreads -> tid0 {release fetch_add; RELAXED poll; acquire fence} ->
//  syncthreads. No __threadfence (release RMW's wbl2 after syncthreads suffices);
//  no per-poll acquire (R8/R9's per-iteration cache maintenance suspected storm).
//  Groups are XCD-local: grp=(bid&7)*2+((bid>>3)&1) -> under round-robin dispatch
//  a group's 16 blocks share one XCD L2 (heuristic only; correctness unaffected).

typedef __attribute__((ext_vector_type(8))) short short8v;   // 8 x bf16
typedef __attribute__((ext_vector_type(4))) float f32x4;

#define HBUF 524288        // elems per H buffer: 16 grp *128*256
#define GSTRIDE 32768      // elems per group: 128*256

static __device__ __forceinline__ unsigned short f2bf(float f) {
  unsigned int u = __float_as_uint(f);
  u += 0x7fffu + ((u >> 16) & 1u);   // RNE
  return (unsigned short)(u >> 16);
}
static __device__ __forceinline__ float bf2f(unsigned short u) {
  return __uint_as_float(((unsigned int)u) << 16);
}
static __device__ __forceinline__ float sigf(float x) { return 1.f / (1.f + __expf(-x)); }
static __device__ __forceinline__ float tanhfast(float x) {
  float xc = fminf(fmaxf(x, -15.f), 15.f);
  float e = __expf(2.f * xc);
  return (e - 1.f) / (e + 1.f);
}
static __device__ __forceinline__ float softplusf(float x) {
  return (x > 0.f) ? (x + log1pf(expf(-x))) : log1pf(expf(x));
}

// ---------------- prep: fragment-major per-slice weights, biases ----------------
__global__ void prep_kernel(const float* __restrict__ Wih0, const float* __restrict__ Whh0,
                            const float* __restrict__ Wih1, const float* __restrict__ Whh1,
                            const float* __restrict__ bih0, const float* __restrict__ bhh0,
                            const float* __restrict__ bih1, const float* __restrict__ bhh1,
                            const float* __restrict__ Wpb,  const float* __restrict__ Wpg,
                            unsigned short* __restrict__ W0, unsigned short* __restrict__ W1,
                            unsigned short* __restrict__ Wp,
                            float* __restrict__ bias0, float* __restrict__ bias1) {
  int i = blockIdx.x * 256 + threadIdx.x;
  if (i < 327680) {            // W0f: [s][g][kk(10)][lane(64)][8]
    int s = i / 20480, rem = i % 20480;
    int g = rem / 5120, rem2 = rem % 5120;
    int kk = rem2 >> 9, lane = (rem2 >> 3) & 63, e = rem2 & 7;
    int n = g * 256 + s * 16 + (lane & 15);
    int k = kk * 32 + (lane >> 4) * 8 + e;
    float v = (k < 64) ? Wih0[n * 64 + k] : Whh0[n * 256 + (k - 64)];
    W0[i] = f2bf(v);
    return;
  }
  i -= 327680;
  if (i < 524288) {            // W1f: [s][g][kk(16)][lane(64)][8]
    int s = i >> 15, rem = i & 32767;
    int g = rem >> 13, rem2 = rem & 8191;
    int kk = rem2 >> 9, lane = (rem2 >> 3) & 63, e = rem2 & 7;
    int n = g * 256 + s * 16 + (lane & 15);
    int k = kk * 32 + (lane >> 4) * 8 + e;
    float v = (k < 256) ? Wih1[n * 256 + k] : Whh1[n * 256 + (k - 256)];
    W1[i] = f2bf(v);
    return;
  }
  i -= 524288;
  if (i < 10752) {             // WpF: [21][512]
    int o = i >> 9, k = i & 511;
    float v = (o == 0) ? Wpb[k] : Wpg[(o - 1) * 512 + k];
    Wp[i] = f2bf(v);
    return;
  }
  i -= 10752;
  if (i < 1024) { bias0[i] = bih0[i] + bhh0[i]; return; }
  i -= 1024;
  if (i < 1024) { bias1[i] = bih1[i] + bhh1[i]; return; }
}

// ---------------- main persistent cooperative kernel ----------------
__global__ __launch_bounds__(512, 2) void lstm_crps_kernel(
    const float* __restrict__ X,      // [2048,96,64]
    const float* __restrict__ Y,      // [2048,96]
    const unsigned short* __restrict__ W0f,
    const unsigned short* __restrict__ W1f,
    const unsigned short* __restrict__ WpF,
    const float* __restrict__ bias0, const float* __restrict__ bias1,
    const float* __restrict__ bpb, const float* __restrict__ bpg,
    unsigned short* __restrict__ H0, unsigned short* __restrict__ H1,
    int* __restrict__ flags,
    float* __restrict__ out) {
  __shared__ __align__(16) unsigned short WL0[20480];   // [4][10][64][8]  40KB
  __shared__ __align__(16) unsigned short WL1[32768];   // [4][16][64][8]  64KB
  __shared__ __align__(16) unsigned short WpL[21 * 520];// padded: bank = o*4 mod 32
  __shared__ float PJ[8][22];
  __shared__ float bpgs[20];
  __shared__ float CB[8][24], KN[8][24];

  const int tid = threadIdx.x;
  const int w  = tid >> 6;     // wave 0..7 = m-tile
  const int l  = tid & 63;
  const int lr = l & 15;
  const int lg = l >> 4;
  const int bid = blockIdx.x;
  // XCD-local grouping (heuristic; correctness independent of mapping)
  const int grp = (bid & 7) * 2 + ((bid >> 3) & 1);   // 0..15
  const int s   = bid >> 4;                           // 0..15 gate-row slice

  // ---- load weight slice into LDS (once)
  {
    const int4* src0 = (const int4*)(W0f + s * 20480);
    int4* dst0 = (int4*)WL0;
    for (int i = tid; i < 2560; i += 512) dst0[i] = src0[i];
    const int4* src1 = (const int4*)(W1f + s * 32768);
    int4* dst1 = (int4*)WL1;
    for (int i = tid; i < 4096; i += 512) dst1[i] = src1[i];
    for (int i = tid; i < 10752; i += 512) {
      int o = i >> 9, k = i & 511;
      WpL[o * 520 + k] = WpF[i];
    }
    if (tid < 20) bpgs[tid] = bpg[tid];
  }

  float bz0[4], bz1[4];
#pragma unroll
  for (int g = 0; g < 4; ++g) {
    int n = g * 256 + 16 * s + lr;
    bz0[g] = bias0[n];
    bz1[g] = bias1[n];
  }
  float c0s[4] = {}, c1s[4] = {};
  float lossacc = 0.f;
  const float bpbv = bpb[0];

  const int myrow = grp * 128 + w * 16 + lr;          // A-frag row
  const float* xrowp = X + (size_t)myrow * 96 * 64 + lg * 8;

  __syncthreads();

  for (int it = 0; it <= 96; ++it) {
    const int tA = it - 1;     // index computed by GEMM1/proj this iter

    // ---- A-frag loads (issue all early; h0(tA) shared by both GEMMs)
    short8v h0f[8], h1f[8];
    if (it >= 1) {
      const unsigned short* hp = H0 + (size_t)(tA & 3) * HBUF + (size_t)myrow * 256 + lg * 8;
#pragma unroll
      for (int kk = 0; kk < 8; ++kk) h0f[kk] = *(const short8v*)(hp + kk * 32);
    }
    if (it >= 2) {             // h1(it-2); (it-2)&1 == it&1
      const unsigned short* hp = H1 + (size_t)(it & 1) * HBUF + (size_t)myrow * 256 + lg * 8;
#pragma unroll
      for (int kk = 0; kk < 8; ++kk) h1f[kk] = *(const short8v*)(hp + kk * 32);
    }
    float4 xa0, xa1, xb0, xb1;
    if (it < 96) {
      const float* xp = xrowp + (size_t)it * 64;
      xa0 = *(const float4*)xp;        xa1 = *(const float4*)(xp + 4);
      xb0 = *(const float4*)(xp + 32); xb1 = *(const float4*)(xp + 36);
    }
    float yv = 0.f;
    if (it >= 1 && tid < 8) yv = Y[(size_t)(grp * 128 + 8 * s + tid) * 96 + tA];

    f32x4 acc[4];

    // ---- step a: GEMM1(tA) = [h0(tA) | h1(tA-1)] @ W1^T -> h1(tA)
    if (it >= 1) {
#pragma unroll
      for (int g = 0; g < 4; ++g) { f32x4 z = {0.f, 0.f, 0.f, 0.f}; acc[g] = z; }
#pragma unroll
      for (int kk = 0; kk < 8; ++kk)
#pragma unroll
        for (int g = 0; g < 4; ++g) {
          short8v b = *(const short8v*)&WL1[((g * 16 + kk) * 64 + l) * 8];
          acc[g] = __builtin_amdgcn_mfma_f32_16x16x32_bf16(h0f[kk], b, acc[g], 0, 0, 0);
        }
      if (it >= 2) {
#pragma unroll
        for (int kk = 0; kk < 8; ++kk)
#pragma unroll
          for (int g = 0; g < 4; ++g) {
            short8v b = *(const short8v*)&WL1[((g * 16 + 8 + kk) * 64 + l) * 8];
            acc[g] = __builtin_amdgcn_mfma_f32_16x16x32_bf16(h1f[kk], b, acc[g], 0, 0, 0);
          }
      }
      unsigned short* h1c = H1 + (size_t)(tA & 1) * HBUF + grp * GSTRIDE;
#pragma unroll
      for (int r = 0; r < 4; ++r) {
        int rowl = w * 16 + lg * 4 + r;
        float cn = sigf(acc[1][r] + bz1[1]) * c1s[r]
                 + sigf(acc[0][r] + bz1[0]) * tanhfast(acc[2][r] + bz1[2]);
        c1s[r] = cn;
        float hn = sigf(acc[3][r] + bz1[3]) * tanhfast(cn);
        h1c[rowl * 256 + 16 * s + lr] = f2bf(hn);
      }
    }

    // ---- step b: GEMM0(it) = [x(it) | h0(it-1)] @ W0^T -> h0(it)
    if (it < 96) {
#pragma unroll
      for (int g = 0; g < 4; ++g) { f32x4 z = {0.f, 0.f, 0.f, 0.f}; acc[g] = z; }
      {
        short8v a0;
        a0[0] = (short)f2bf(xa0.x); a0[1] = (short)f2bf(xa0.y);
        a0[2] = (short)f2bf(xa0.z); a0[3] = (short)f2bf(xa0.w);
        a0[4] = (short)f2bf(xa1.x); a0[5] = (short)f2bf(xa1.y);
        a0[6] = (short)f2bf(xa1.z); a0[7] = (short)f2bf(xa1.w);
#pragma unroll
        for (int g = 0; g < 4; ++g) {
          short8v b = *(const short8v*)&WL0[((g * 10 + 0) * 64 + l) * 8];
          acc[g] = __builtin_amdgcn_mfma_f32_16x16x32_bf16(a0, b, acc[g], 0, 0, 0);
        }
        short8v a1;
        a1[0] = (short)f2bf(xb0.x); a1[1] = (short)f2bf(xb0.y);
        a1[2] = (short)f2bf(xb0.z); a1[3] = (short)f2bf(xb0.w);
        a1[4] = (short)f2bf(xb1.x); a1[5] = (short)f2bf(xb1.y);
        a1[6] = (short)f2bf(xb1.z); a1[7] = (short)f2bf(xb1.w);
#pragma unroll
        for (int g = 0; g < 4; ++g) {
          short8v b = *(const short8v*)&WL0[((g * 10 + 1) * 64 + l) * 8];
          acc[g] = __builtin_amdgcn_mfma_f32_16x16x32_bf16(a1, b, acc[g], 0, 0, 0);
        }
      }
      if (it >= 1) {
#pragma unroll
        for (int kk = 0; kk < 8; ++kk)
#pragma unroll
          for (int g = 0; g < 4; ++g) {
            short8v b = *(const short8v*)&WL0[((g * 10 + 2 + kk) * 64 + l) * 8];
            acc[g] = __builtin_amdgcn_mfma_f32_16x16x32_bf16(h0f[kk], b, acc[g], 0, 0, 0);
          }
      }
      unsigned short* h0c = H0 + (size_t)(it & 3) * HBUF + grp * GSTRIDE;
#pragma unroll
      for (int r = 0; r < 4; ++r) {
        int rowl = w * 16 + lg * 4 + r;
        float cn = sigf(acc[1][r] + bz0[1]) * c0s[r]
                 + sigf(acc[0][r] + bz0[0]) * tanhfast(acc[2][r] + bz0[2]);
        c0s[r] = cn;
        float hn = sigf(acc[3][r] + bz0[3]) * tanhfast(cn);
        h0c[rowl * 256 + 16 * s + lr] = f2bf(hn);
      }
    }

    // ---- single sync: h1(tA) and h0(it) visible group-wide
    __syncthreads();     // drains all vmem stores (compiler waitcnt before barrier)
    if (tid == 0) {
      int* f = flags + (it * 16 + grp) * 32;   // private 128B line
      __hip_atomic_fetch_add(f, 1, __ATOMIC_RELEASE, __HIP_MEMORY_SCOPE_AGENT);
      while (__hip_atomic_load(f, __ATOMIC_RELAXED, __HIP_MEMORY_SCOPE_AGENT) < 16)
        __builtin_amdgcn_s_sleep(2);
      __builtin_amdgcn_fence(__ATOMIC_ACQUIRE, "agent");
    }
    __syncthreads();

    // ---- step c: projection + CRPS for tA
    if (it >= 1) {
      if (tid < 168) {   // o-major: 8 lanes share one o (LDS broadcast)
        int o = tid >> 3, r = tid & 7;
        const unsigned short* h0p = H0 + (size_t)(tA & 3) * HBUF
                                    + (size_t)(grp * 128 + 8 * s + r) * 256;
        const unsigned short* h1p = H1 + (size_t)(tA & 1) * HBUF
                                    + (size_t)(grp * 128 + 8 * s + r) * 256;
        const unsigned short* wpo = &WpL[o * 520];
        float a = 0.f;
#pragma unroll 4
        for (int cb = 0; cb < 32; ++cb) {
          short8v v0 = *(const short8v*)(h0p + cb * 8);
          short8v v1 = *(const short8v*)(h1p + cb * 8);
          short8v w0 = *(const short8v*)(wpo + cb * 16);
          short8v w1 = *(const short8v*)(wpo + cb * 16 + 8);
#pragma unroll
          for (int e = 0; e < 4; ++e) {
            a += bf2f((unsigned short)v0[e]) * bf2f((unsigned short)w0[2 * e])
               + bf2f((unsigned short)v1[e]) * bf2f((unsigned short)w0[2 * e + 1]);
          }
#pragma unroll
          for (int e = 4; e < 8; ++e) {
            a += bf2f((unsigned short)v0[e]) * bf2f((unsigned short)w1[2 * e - 8])
               + bf2f((unsigned short)v1[e]) * bf2f((unsigned short)w1[2 * e - 7]);
          }
        }
        PJ[r][o] = a + ((o == 0) ? bpbv : bpgs[o - 1]);
      }
      __syncthreads();

      if (tid < 8) {
        const int row = tid;
        const float y = yv;
        const float h = 0.05f;
        float beta0 = softplusf(PJ[row][0]);
        {  // pass 1: spline coeffs bb -> CB
          float gprev = beta0, brawprev = 0.f, ssum = 0.f, g19 = 0.f;
#pragma unroll
          for (int i2 = 0; i2 < 20; ++i2) {
            float gi = softplusf(PJ[row][1 + i2]);
            float braw = (gi - gprev) * 10.f;
            float bbv = (i2 == 0) ? braw : (braw - brawprev);
            if (i2 < 19) { ssum += bbv; CB[row][i2] = bbv; }
            gprev = gi; brawprev = braw; g19 = gi;
          }
          CB[row][19] = g19 - ssum;
        }
        {  // pass 2: knots via prefix sums
          float S0 = 0.f, S1 = 0.f, S2 = 0.f;
          KN[row][0] = 0.f;
#pragma unroll
          for (int i2 = 0; i2 < 19; ++i2) {
            float bbv = CB[row][i2];
            float fi = (float)i2;
            S0 += bbv; S1 += fi * bbv; S2 += fi * fi * bbv;
            float ip = (float)(i2 + 1);
            KN[row][i2 + 1] = ip * h * beta0 + h * h * (ip * ip * S0 - 2.f * ip * S1 + S2);
          }
        }
        float Aq = 0.f, Bk = 0.f, Ck = 0.f, crps3 = 0.f;
        float best = 1e30f; int amin = 0;
#pragma unroll
        for (int i2 = 0; i2 < 20; ++i2) {
          float knot = KN[row][i2];
          float bbv = CB[row][i2];
          float d = y - knot;
          float ad = fabsf(d);
          if (ad < best) { best = ad; amin = i2; }
          float alf = (d > 0.f) ? 1.f : 0.f;
          float ks = (float)i2 * h;
          float ab = alf * bbv;
          Aq += ab; Bk += ab * ks; Ck += ab * ks * ks;
          float om = 1.f - ks; float om2 = om * om;
          crps3 += bbv * (1.f / 6.f) * om2 * om2;
        }
        float Bc = beta0 - 2.f * Bk;
        float Cc = Ck - y;
        float disc = Bc * Bc - 4.f * Aq * Cc;
        bool az = (Aq == 0.f);
        bool qs = (!az) && (disc >= 0.f);
        float alpha;
        if (qs)      alpha = (-Bc + sqrtf(disc)) / (2.f * Aq);
        else if (az) alpha = -Cc / ((Bc == 0.f) ? 1.f : Bc);
        else         alpha = (float)amin * h;
        float crps4 = 0.f;
#pragma unroll
        for (int i2 = 0; i2 < 20; ++i2) {
          float knot = KN[row][i2];
          float bbv = CB[row][i2];
          float alf = ((y - knot) > 0.f) ? 1.f : 0.f;
          float am = alpha - (float)i2 * h;
          crps4 += alf * (2.f / 3.f) * bbv * am * am * am;
        }
        lossacc += (-y * (1.f - 2.f * alpha) + beta0 * (1.f / 3.f - alpha * alpha)
                    + crps3 - crps4);
      }
      // no trailing barrier: next PJ write is separated by the next iter's
      // two sync-barriers.
    }
  }

  // block reduction: lanes 0..7 of wave 0 hold loss
  if (w == 0) {
#pragma unroll
    for (int off = 4; off > 0; off >>= 1) lossacc += __shfl_down(lossacc, off, 64);
    if (l == 0) atomicAdd(out, lossacc * (1.f / 2048.f));
  }
}

extern "C" void kernel_launch(void* const* d_in, const int* in_sizes, int n_in,
                              void* d_out, int out_size, void* d_ws, size_t ws_size,
                              hipStream_t stream) {
  const float* X    = (const float*)d_in[0];
  const float* Y    = (const float*)d_in[1];
  const float* Wih0 = (const float*)d_in[2];
  const float* Whh0 = (const float*)d_in[3];
  const float* Wih1 = (const float*)d_in[4];
  const float* Whh1 = (const float*)d_in[5];
  const float* bih0 = (const float*)d_in[6];
  const float* bhh0 = (const float*)d_in[7];
  const float* bih1 = (const float*)d_in[8];
  const float* bhh1 = (const float*)d_in[9];
  const float* Wpb  = (const float*)d_in[10];
  const float* bpb  = (const float*)d_in[11];
  const float* Wpg  = (const float*)d_in[12];
  const float* bpg  = (const float*)d_in[13];

  char* ws = (char*)d_ws;
  unsigned short* W0f = (unsigned short*)(ws);                // 655,360
  unsigned short* W1f = (unsigned short*)(ws + 655360);       // 1,048,576 -> 1,703,936
  unsigned short* WpF = (unsigned short*)(ws + 1703936);      // 21,504
  float* bias0 = (float*)(ws + 1725440);                      // 4,096
  float* bias1 = (float*)(ws + 1729536);                      // 4,096
  unsigned short* H0 = (unsigned short*)(ws + 1736704);       // 4 x 1MB ring = 4,194,304
  unsigned short* H1 = (unsigned short*)(ws + 5931008);       // 2 x 1MB ring = 2,097,152
  int* flags = (int*)(ws + 8028160);                          // 97*16*32*4 = 198,656

  hipMemsetAsync(d_out, 0, sizeof(float), stream);
  hipMemsetAsync(flags, 0, 198656, stream);
  prep_kernel<<<3378, 256, 0, stream>>>(Wih0, Whh0, Wih1, Whh1, bih0, bhh0, bih1, bhh1,
                                        Wpb, Wpg, W0f, W1f, WpF, bias0, bias1);

  float* outp = (float*)d_out;
  void* kargs[] = {(void*)&X, (void*)&Y, (void*)&W0f, (void*)&W1f, (void*)&WpF,
                   (void*)&bias0, (void*)&bias1, (void*)&bpb, (void*)&bpg,
                   (void*)&H0, (void*)&H1, (void*)&flags, (void*)&outp};
  hipLaunchCooperativeKernel((const void*)lstm_crps_kernel, dim3(256), dim3(512),
                             kargs, 0, stream);
}